// Round 13
// baseline (155.955 us; speedup 1.0000x reference)
//
#include <hip/hip_runtime.h>
#include <cstddef>

#define NN 3072
#define RR 16
#define NB 16
#define FILL_BLOCKS 2048
#define FILL_ITERS 72   // NN*NN*4 quads / (FILL_BLOCKS*256) = 72 exactly

typedef float f32x4 __attribute__((ext_vector_type(4)));

// Prologue: key[i] = valid ? batch[i] : -1, plus batch row boundaries
// start[b] = first row with batch >= b (batch sorted). start[NB]=NN.
__global__ void frd_prep_kernel(const int* __restrict__ cls,
                                const int* __restrict__ batch,
                                int* __restrict__ key,
                                int* __restrict__ start) {
    int t = blockIdx.x * blockDim.x + threadIdx.x;
    if (t < NN) {
        int c = cls[t];
        int b = batch[t];
        key[t] = (c != 24 && c != 25 && c != 26) ? b : -1;
        int prev = (t == 0) ? -1 : batch[t - 1];
        for (int bb = prev + 1; bb <= b; ++bb) start[bb] = t;
        if (t == NN - 1)
            for (int bb = b + 1; bb <= NB; ++bb) start[bb] = NN;
    }
}

// Phase 1: PURE unconditional fill of the default pattern. No loads, no
// masks, plain stores, pointer-bump grid-stride — mirrors the rocclr
// fillBufferAligned structure that measures 6.7 TB/s on this device.
// Lane t covers quad q=(t&3): (1,0,0,0) for q==0 else zeros -> the
// one_hot(0,16) row pattern repeats every 4 lanes; coalesced 1 KB bursts.
__global__ __launch_bounds__(256)
void frd_fill_kernel(float* __restrict__ out) {
    const int t = blockIdx.x * 256 + threadIdx.x;        // [0, 524288)
    const float d0 = ((t & 3) == 0) ? 1.0f : 0.0f;
    const f32x4 r = {d0, 0.0f, 0.0f, 0.0f};
    float* p = out + (size_t)t * 4;
    const size_t step = (size_t)FILL_BLOCKS * 256 * 4;   // floats per sweep
#pragma unroll 4
    for (int it = 0; it < FILL_ITERS; ++it) {
        *reinterpret_cast<f32x4*>(p) = r;
        p += step;
    }
}

// Phase 3: overwrite true pairs only. One block per row i (exit if key
// invalid). 4 lanes per pair (lane q writes quad q) -> each written pair is
// one full 64 B line, coalesced across the wave. Sweeps row i's batch range.
__global__ __launch_bounds__(256)
void frd_diag_kernel(const float* __restrict__ z1,
                     const float* __restrict__ z2,
                     const float* __restrict__ seg,
                     const int* __restrict__ key,
                     const int* __restrict__ start,
                     float* __restrict__ out) {
    const int i = blockIdx.x;
    const int ki = key[i];
    if (ki < 0) return;
    const int s0 = start[ki];
    const int s1 = start[ki + 1];
    const int q = threadIdx.x & 3;
    const int g = threadIdx.x >> 2;       // pair group [0,64)

    const float4 a = *reinterpret_cast<const float4*>(z1 + i * RR + q * 4);

    for (int j = s0 + g; j < s1; j += 64) {
        if (key[j] != ki) continue;                   // fill's default stands
        const float s = seg[i * NN + j];              // 4-lane broadcast
        const float seg_eff = s + ((i == j) ? 1.0f : 0.0f);
        if (seg_eff != 0.0f) continue;                // default stands
        const float4 b = *reinterpret_cast<const float4*>(z2 + j * RR + q * 4);
        f32x4 r;
        r.x = a.x * b.x; r.y = a.y * b.y; r.z = a.z * b.z; r.w = a.w * b.w;
        float* op = out + ((size_t)i * NN + j) * RR + q * 4;
        __builtin_nontemporal_store(r, reinterpret_cast<f32x4*>(op));
    }
}

extern "C" void kernel_launch(void* const* d_in, const int* in_sizes, int n_in,
                              void* d_out, int out_size, void* d_ws, size_t ws_size,
                              hipStream_t stream) {
    const float* z1  = (const float*)d_in[0];
    const float* z2  = (const float*)d_in[1];
    const float* seg = (const float*)d_in[2];
    const int* cls   = (const int*)d_in[3];
    const int* batch = (const int*)d_in[4];
    float* out = (float*)d_out;
    int* key   = (int*)d_ws;
    int* start = key + NN;

    frd_fill_kernel<<<FILL_BLOCKS, 256, 0, stream>>>(out);
    frd_prep_kernel<<<(NN + 255) / 256, 256, 0, stream>>>(cls, batch, key, start);
    frd_diag_kernel<<<NN, 256, 0, stream>>>(z1, z2, seg, key, start, out);
}

// Round 14
// 114.326 us; speedup vs baseline: 1.3641x; 1.3641x over previous
//
#include <hip/hip_runtime.h>
#include <cstddef>

#define NN 3072
#define RR 16
#define NB 16
#define FILL_BLOCKS 256
#define FILL_ITERS 576   // NN*NN*4 quads / (FILL_BLOCKS*256 threads) = 576 exactly

typedef float f32x4 __attribute__((ext_vector_type(4)));

// Prologue: key[i] = valid ? batch[i] : -1, plus batch row boundaries
// start[b] = first row with batch >= b (batch sorted). start[NB]=NN.
__global__ void frd_prep_kernel(const int* __restrict__ cls,
                                const int* __restrict__ batch,
                                int* __restrict__ key,
                                int* __restrict__ start) {
    int t = blockIdx.x * blockDim.x + threadIdx.x;
    if (t < NN) {
        int c = cls[t];
        int b = batch[t];
        key[t] = (c != 24 && c != 25 && c != 26) ? b : -1;
        int prev = (t == 0) ? -1 : batch[t - 1];
        for (int bb = prev + 1; bb <= b; ++bb) start[bb] = t;
        if (t == NN - 1)
            for (int bb = b + 1; bb <= NB; ++bb) start[bb] = NN;
    }
}

// Phase 1: pure fill at rocclr-fill concurrency — 256 blocks (1/CU, 1 wave/
// SIMD), each thread walks 576 grid-stride iterations. Low stream count keeps
// per-HBM-channel writes row-sequential; NT stores preserve burst order.
__global__ __launch_bounds__(256)
void frd_fill_kernel(float* __restrict__ out) {
    const int t = blockIdx.x * 256 + threadIdx.x;        // [0, 65536)
    const float d0 = ((t & 3) == 0) ? 1.0f : 0.0f;
    const f32x4 r = {d0, 0.0f, 0.0f, 0.0f};
    float* p = out + (size_t)t * 4;
    const size_t step = (size_t)FILL_BLOCKS * 256 * 4;   // 1 MB in floats
#pragma unroll 8
    for (int it = 0; it < FILL_ITERS; ++it) {
        __builtin_nontemporal_store(r, reinterpret_cast<f32x4*>(p));
        p += step;
    }
}

// Phase 3: overwrite true pairs only. One block per row i (exit if key
// invalid). 4 lanes per pair (lane q writes quad q) -> each written pair is
// one full 64 B line, coalesced across the wave. Sweeps row i's batch range.
__global__ __launch_bounds__(256)
void frd_diag_kernel(const float* __restrict__ z1,
                     const float* __restrict__ z2,
                     const float* __restrict__ seg,
                     const int* __restrict__ key,
                     const int* __restrict__ start,
                     float* __restrict__ out) {
    const int i = blockIdx.x;
    const int ki = key[i];
    if (ki < 0) return;
    const int s0 = start[ki];
    const int s1 = start[ki + 1];
    const int q = threadIdx.x & 3;
    const int g = threadIdx.x >> 2;       // pair group [0,64)

    const float4 a = *reinterpret_cast<const float4*>(z1 + i * RR + q * 4);

    for (int j = s0 + g; j < s1; j += 64) {
        if (key[j] != ki) continue;                   // fill's default stands
        const float s = seg[i * NN + j];              // 4-lane broadcast
        const float seg_eff = s + ((i == j) ? 1.0f : 0.0f);
        if (seg_eff != 0.0f) continue;                // default stands
        const float4 b = *reinterpret_cast<const float4*>(z2 + j * RR + q * 4);
        f32x4 r;
        r.x = a.x * b.x; r.y = a.y * b.y; r.z = a.z * b.z; r.w = a.w * b.w;
        float* op = out + ((size_t)i * NN + j) * RR + q * 4;
        __builtin_nontemporal_store(r, reinterpret_cast<f32x4*>(op));
    }
}

extern "C" void kernel_launch(void* const* d_in, const int* in_sizes, int n_in,
                              void* d_out, int out_size, void* d_ws, size_t ws_size,
                              hipStream_t stream) {
    const float* z1  = (const float*)d_in[0];
    const float* z2  = (const float*)d_in[1];
    const float* seg = (const float*)d_in[2];
    const int* cls   = (const int*)d_in[3];
    const int* batch = (const int*)d_in[4];
    float* out = (float*)d_out;
    int* key   = (int*)d_ws;
    int* start = key + NN;

    frd_fill_kernel<<<FILL_BLOCKS, 256, 0, stream>>>(out);
    frd_prep_kernel<<<(NN + 255) / 256, 256, 0, stream>>>(cls, batch, key, start);
    frd_diag_kernel<<<NN, 256, 0, stream>>>(z1, z2, seg, key, start, out);
}